// Round 4
// baseline (299.679 us; speedup 1.0000x reference)
//
#include <hip/hip_runtime.h>

// CommLayer: y[b,a,e] = tanh( xb[b,a,:]·M[e,:] + S[b,:]·Cn[e,:] ),
//   M = H - C/7, Cn = C/7, S[b] = sum_a xb[b,a,:].
// K=128 fp16 MFMA GEMM, A_aug[m=(b,a)] = [xb | S(b)], B_aug[e] = [M[e] | Cn[e]].
// R4 = R3 with the nontemporal-store type fixed (ext_vector_type, not
// HIP_vector_type). Register-diet for occupancy: weights in LDS (one barrier),
// B-fragments ds_read per tile, fp16 packed butterfly for S, transposed MFMA
// (weights as A-operand) -> float4 nontemporal stores.
// Target: <=64 total regs -> 8 waves/SIMD; memory floor ~41 us.

typedef _Float16 half4v  __attribute__((ext_vector_type(4)));
typedef _Float16 half8v  __attribute__((ext_vector_type(8)));
typedef float    floatx4 __attribute__((ext_vector_type(4)));

#define WAVES_PER_BLOCK 4
#define TILES_PER_WAVE  4
#define BSTRIDE 136   // halfs per augB row: 128 + 8 pad (16B-aligned, breaks pow2 banks)

__device__ __forceinline__ half8v h8_bfly_add(half8v v, int mask) {
    union { half8v h; int i[4]; } u, r;
    u.h = v;
    #pragma unroll
    for (int k = 0; k < 4; ++k) r.i[k] = __shfl_xor(u.i[k], mask, 64);
    return v + r.h;   // v_pk_add_f16 x4
}

__global__ __launch_bounds__(256, 8)
void comm_kernel(const float* __restrict__ x,
                 const float* __restrict__ Hw,
                 const float* __restrict__ Cw,
                 float* __restrict__ out)
{
    __shared__ __align__(16) _Float16 augB[64 * BSTRIDE];  // 17408 B

    const int tid  = threadIdx.x;
    const int lane = tid & 63;
    const int wave = tid >> 6;
    const int quad = lane >> 4;   // 0..3
    const int l16  = lane & 15;

    // ---- Stage 0 (once per block): build augmented B in LDS ----
    // augB[e][k<64] = H[e][k] - C[e][k]/7 ; augB[e][64+k] = C[e][k]/7
    #pragma unroll
    for (int i = 0; i < 4; ++i) {
        const int idx = i * 256 + tid;        // 0..1023 float4-chunks
        const int e = idx >> 4;
        const int k = (idx & 15) << 2;
        const float4 h = *reinterpret_cast<const float4*>(Hw + e * 64 + k);
        const float4 c = *reinterpret_cast<const float4*>(Cw + e * 64 + k);
        half4v m4, c4;
        m4[0] = (_Float16)(h.x - c.x * (1.0f / 7.0f)); c4[0] = (_Float16)(c.x * (1.0f / 7.0f));
        m4[1] = (_Float16)(h.y - c.y * (1.0f / 7.0f)); c4[1] = (_Float16)(c.y * (1.0f / 7.0f));
        m4[2] = (_Float16)(h.z - c.z * (1.0f / 7.0f)); c4[2] = (_Float16)(c.z * (1.0f / 7.0f));
        m4[3] = (_Float16)(h.w - c.w * (1.0f / 7.0f)); c4[3] = (_Float16)(c.w * (1.0f / 7.0f));
        *reinterpret_cast<half4v*>(&augB[e * BSTRIDE + k])      = m4;
        *reinterpret_cast<half4v*>(&augB[e * BSTRIDE + 64 + k]) = c4;
    }
    __syncthreads();   // the only barrier

    const int wgid = blockIdx.x * WAVES_PER_BLOCK + wave;
    const int t0   = wgid * TILES_PER_WAVE;

    #pragma unroll 1
    for (int i = 0; i < TILES_PER_WAVE; ++i) {
        const int t = t0 + i;

        // ---- x fragments (B-operand layout: n = l16, k = quad*8 + j) ----
        const float* xt = x + (size_t)t * 1024 + l16 * 64 + quad * 8;
        float4 v0 = *reinterpret_cast<const float4*>(xt);
        float4 v1 = *reinterpret_cast<const float4*>(xt + 4);
        float4 v2 = *reinterpret_cast<const float4*>(xt + 32);
        float4 v3 = *reinterpret_cast<const float4*>(xt + 36);

        half8v a0, a1;   // kt=0 (k 0..31), kt=1 (k 32..63)
        a0[0]=(_Float16)v0.x; a0[1]=(_Float16)v0.y; a0[2]=(_Float16)v0.z; a0[3]=(_Float16)v0.w;
        a0[4]=(_Float16)v1.x; a0[5]=(_Float16)v1.y; a0[6]=(_Float16)v1.z; a0[7]=(_Float16)v1.w;
        a1[0]=(_Float16)v2.x; a1[1]=(_Float16)v2.y; a1[2]=(_Float16)v2.z; a1[3]=(_Float16)v2.w;
        a1[4]=(_Float16)v3.x; a1[5]=(_Float16)v3.y; a1[6]=(_Float16)v3.z; a1[7]=(_Float16)v3.w;

        // ---- S via packed fp16 butterfly over the 8 agent-lanes (l16 bits 0..2).
        // Result lands broadcast to every lane = kt=2,3 augmented-A fragment. ----
        half8v s0 = a0, s1 = a1;
        #pragma unroll
        for (int m = 1; m <= 4; m <<= 1) {
            s0 = h8_bfly_add(s0, m);
            s1 = h8_bfly_add(s1, m);
        }

        // ---- MFMA, transposed: D[e'][m'] with weights as A-operand ----
        floatx4 acc[4];
        #pragma unroll
        for (int nt = 0; nt < 4; ++nt) acc[nt] = floatx4{0.f, 0.f, 0.f, 0.f};

        #pragma unroll
        for (int nt = 0; nt < 4; ++nt) {
            const _Float16* bp = &augB[(nt * 16 + l16) * BSTRIDE + quad * 8];
            const half8v b0 = *reinterpret_cast<const half8v*>(bp);
            const half8v b1 = *reinterpret_cast<const half8v*>(bp + 32);
            const half8v b2 = *reinterpret_cast<const half8v*>(bp + 64);
            const half8v b3 = *reinterpret_cast<const half8v*>(bp + 96);
            acc[nt] = __builtin_amdgcn_mfma_f32_16x16x32_f16(b0, a0, acc[nt], 0, 0, 0);
            acc[nt] = __builtin_amdgcn_mfma_f32_16x16x32_f16(b1, a1, acc[nt], 0, 0, 0);
            acc[nt] = __builtin_amdgcn_mfma_f32_16x16x32_f16(b2, s0, acc[nt], 0, 0, 0);
            acc[nt] = __builtin_amdgcn_mfma_f32_16x16x32_f16(b3, s1, acc[nt], 0, 0, 0);
        }

        // ---- Epilogue: C/D col = l16 = agent-row, row = quad*4+reg = e within nt-tile.
        // Four consecutive e per lane -> float4 (ext-vector) nontemporal stores. ----
        float* o = out + (size_t)t * 1024 + l16 * 64 + quad * 4;
        #pragma unroll
        for (int nt = 0; nt < 4; ++nt) {
            floatx4 r;
            #pragma unroll
            for (int reg = 0; reg < 4; ++reg) {
                float y = acc[nt][reg];
                y = fminf(10.f, fmaxf(-10.f, y));
                const float tv  = __builtin_amdgcn_exp2f(y * 2.8853900817779268f); // e^{2y}
                r[reg] = (tv - 1.f) * __builtin_amdgcn_rcpf(tv + 1.f);
            }
            __builtin_nontemporal_store(r, reinterpret_cast<floatx4*>(o + nt * 16));
        }
    }
}

extern "C" void kernel_launch(void* const* d_in, const int* in_sizes, int n_in,
                              void* d_out, int out_size, void* d_ws, size_t ws_size,
                              hipStream_t stream) {
    const float* x  = (const float*)d_in[0];
    const float* Hw = (const float*)d_in[1];
    const float* Cw = (const float*)d_in[2];
    float* out = (float*)d_out;

    const int rows   = in_sizes[0] / 512;                       // 65536 batch rows
    const int ntiles = rows * 8 / 16;                           // 32768 m-tiles
    const int blocks = ntiles / (WAVES_PER_BLOCK * TILES_PER_WAVE); // 2048
    comm_kernel<<<blocks, 256, 0, stream>>>(x, Hw, Cw, out);
}

// Round 5
// 240.679 us; speedup vs baseline: 1.2451x; 1.2451x over previous
//
#include <hip/hip_runtime.h>

// CommLayer: y[b,a,e] = tanh( xb[b,a,:]·M[e,:] + S[b,:]·Cn[e,:] ),
//   M = H - C/7, Cn = C/7, S[b] = sum_a xb[b,a,:].
// K=128 fp16 MFMA GEMM, A_aug[m=(b,a)] = [xb | S(b)], B_aug[e] = [M[e] | Cn[e]].
// R5: R4 minus the nontemporal stores (they caused partial-line write
// amplification + write-allocate fetches at HBM: 455 MB traffic), plus a
// manual one-tile read prefetch for MLP. Weights in LDS (one barrier),
// B-fragments ds_read per tile, fp16 packed butterfly for S, transposed MFMA
// (weights as A-operand) -> dwordx4 stores that L2 merges into full lines.

typedef _Float16 half4v  __attribute__((ext_vector_type(4)));
typedef _Float16 half8v  __attribute__((ext_vector_type(8)));
typedef float    floatx4 __attribute__((ext_vector_type(4)));

#define WAVES_PER_BLOCK 4
#define TILES_PER_WAVE  4
#define BSTRIDE 136   // halfs per augB row: 128 + 8 pad (16B-aligned)

__device__ __forceinline__ half8v h8_bfly_add(half8v v, int mask) {
    union { half8v h; int i[4]; } u, r;
    u.h = v;
    #pragma unroll
    for (int k = 0; k < 4; ++k) r.i[k] = __shfl_xor(u.i[k], mask, 64);
    return v + r.h;   // v_pk_add_f16 x4
}

__global__ __launch_bounds__(256, 8)
void comm_kernel(const float* __restrict__ x,
                 const float* __restrict__ Hw,
                 const float* __restrict__ Cw,
                 float* __restrict__ out)
{
    __shared__ __align__(16) _Float16 augB[64 * BSTRIDE];  // 17408 B

    const int tid  = threadIdx.x;
    const int lane = tid & 63;
    const int wave = tid >> 6;
    const int quad = lane >> 4;   // 0..3
    const int l16  = lane & 15;

    // ---- Stage 0 (once per block): build augmented B in LDS ----
    // augB[e][k<64] = H[e][k] - C[e][k]/7 ; augB[e][64+k] = C[e][k]/7
    #pragma unroll
    for (int i = 0; i < 4; ++i) {
        const int idx = i * 256 + tid;        // 0..1023 float4-chunks
        const int e = idx >> 4;
        const int k = (idx & 15) << 2;
        const float4 h = *reinterpret_cast<const float4*>(Hw + e * 64 + k);
        const float4 c = *reinterpret_cast<const float4*>(Cw + e * 64 + k);
        half4v m4, c4;
        m4[0] = (_Float16)(h.x - c.x * (1.0f / 7.0f)); c4[0] = (_Float16)(c.x * (1.0f / 7.0f));
        m4[1] = (_Float16)(h.y - c.y * (1.0f / 7.0f)); c4[1] = (_Float16)(c.y * (1.0f / 7.0f));
        m4[2] = (_Float16)(h.z - c.z * (1.0f / 7.0f)); c4[2] = (_Float16)(c.z * (1.0f / 7.0f));
        m4[3] = (_Float16)(h.w - c.w * (1.0f / 7.0f)); c4[3] = (_Float16)(c.w * (1.0f / 7.0f));
        *reinterpret_cast<half4v*>(&augB[e * BSTRIDE + k])      = m4;
        *reinterpret_cast<half4v*>(&augB[e * BSTRIDE + 64 + k]) = c4;
    }
    __syncthreads();   // the only barrier

    const int wgid = blockIdx.x * WAVES_PER_BLOCK + wave;
    // Per-lane base for this wave's 4 consecutive tiles.
    const float* xbase = x + (size_t)wgid * TILES_PER_WAVE * 1024 + l16 * 64 + quad * 8;
    float* obase = out + (size_t)wgid * TILES_PER_WAVE * 1024 + l16 * 64 + quad * 4;

    // ---- Prime the software pipeline: tile 0 loads ----
    float4 v0 = *reinterpret_cast<const float4*>(xbase);
    float4 v1 = *reinterpret_cast<const float4*>(xbase + 4);
    float4 v2 = *reinterpret_cast<const float4*>(xbase + 32);
    float4 v3 = *reinterpret_cast<const float4*>(xbase + 36);

    #pragma unroll
    for (int i = 0; i < TILES_PER_WAVE; ++i) {
        // ---- Prefetch tile i+1 before tile i's dependent chain ----
        float4 w0, w1, w2, w3;
        if (i + 1 < TILES_PER_WAVE) {
            const float* xn = xbase + (i + 1) * 1024;
            w0 = *reinterpret_cast<const float4*>(xn);
            w1 = *reinterpret_cast<const float4*>(xn + 4);
            w2 = *reinterpret_cast<const float4*>(xn + 32);
            w3 = *reinterpret_cast<const float4*>(xn + 36);
        }

        // ---- x fragments (B-operand layout: n = l16, k = quad*8 + j) ----
        half8v a0, a1;   // kt=0 (k 0..31), kt=1 (k 32..63)
        a0[0]=(_Float16)v0.x; a0[1]=(_Float16)v0.y; a0[2]=(_Float16)v0.z; a0[3]=(_Float16)v0.w;
        a0[4]=(_Float16)v1.x; a0[5]=(_Float16)v1.y; a0[6]=(_Float16)v1.z; a0[7]=(_Float16)v1.w;
        a1[0]=(_Float16)v2.x; a1[1]=(_Float16)v2.y; a1[2]=(_Float16)v2.z; a1[3]=(_Float16)v2.w;
        a1[4]=(_Float16)v3.x; a1[5]=(_Float16)v3.y; a1[6]=(_Float16)v3.z; a1[7]=(_Float16)v3.w;

        // ---- S via packed fp16 butterfly over the 8 agent-lanes (l16 bits 0..2).
        // Result is broadcast to every lane = kt=2,3 augmented fragment. ----
        half8v s0 = a0, s1 = a1;
        #pragma unroll
        for (int m = 1; m <= 4; m <<= 1) {
            s0 = h8_bfly_add(s0, m);
            s1 = h8_bfly_add(s1, m);
        }

        // ---- MFMA, transposed: weights as A-operand ----
        floatx4 acc[4];
        #pragma unroll
        for (int nt = 0; nt < 4; ++nt) acc[nt] = floatx4{0.f, 0.f, 0.f, 0.f};

        #pragma unroll
        for (int nt = 0; nt < 4; ++nt) {
            const _Float16* bp = &augB[(nt * 16 + l16) * BSTRIDE + quad * 8];
            const half8v b0 = *reinterpret_cast<const half8v*>(bp);
            const half8v b1 = *reinterpret_cast<const half8v*>(bp + 32);
            const half8v b2 = *reinterpret_cast<const half8v*>(bp + 64);
            const half8v b3 = *reinterpret_cast<const half8v*>(bp + 96);
            acc[nt] = __builtin_amdgcn_mfma_f32_16x16x32_f16(b0, a0, acc[nt], 0, 0, 0);
            acc[nt] = __builtin_amdgcn_mfma_f32_16x16x32_f16(b1, a1, acc[nt], 0, 0, 0);
            acc[nt] = __builtin_amdgcn_mfma_f32_16x16x32_f16(b2, s0, acc[nt], 0, 0, 0);
            acc[nt] = __builtin_amdgcn_mfma_f32_16x16x32_f16(b3, s1, acc[nt], 0, 0, 0);
        }

        // ---- Epilogue: C/D col = l16 = agent-row, row = quad*4+reg = e offset.
        // Lane writes 16B at l16*256B + nt*64B + quad*16B: quads form 64B runs,
        // nt pairs complete 128B lines -> L2 merges (plain stores, no nt). ----
        float* o = obase + i * 1024;
        #pragma unroll
        for (int nt = 0; nt < 4; ++nt) {
            floatx4 r;
            #pragma unroll
            for (int reg = 0; reg < 4; ++reg) {
                float y = acc[nt][reg];
                y = fminf(10.f, fmaxf(-10.f, y));
                const float tv  = __builtin_amdgcn_exp2f(y * 2.8853900817779268f); // e^{2y}
                r[reg] = (tv - 1.f) * __builtin_amdgcn_rcpf(tv + 1.f);
            }
            *reinterpret_cast<floatx4*>(o + nt * 16) = r;
        }

        v0 = w0; v1 = w1; v2 = w2; v3 = w3;
    }
}

extern "C" void kernel_launch(void* const* d_in, const int* in_sizes, int n_in,
                              void* d_out, int out_size, void* d_ws, size_t ws_size,
                              hipStream_t stream) {
    const float* x  = (const float*)d_in[0];
    const float* Hw = (const float*)d_in[1];
    const float* Cw = (const float*)d_in[2];
    float* out = (float*)d_out;

    const int rows   = in_sizes[0] / 512;                       // 65536 batch rows
    const int ntiles = rows * 8 / 16;                           // 32768 m-tiles
    const int blocks = ntiles / (WAVES_PER_BLOCK * TILES_PER_WAVE); // 2048
    comm_kernel<<<blocks, 256, 0, stream>>>(x, Hw, Cw, out);
}